// Round 1
// baseline (598.790 us; speedup 1.0000x reference)
//
#include <hip/hip_runtime.h>

#define NBATCH 1024
#define N0     25
#define N1     10
#define NLEAF  (N0 * N1)   // 250
#define SPLITS 4
// embedding dim = 128 f32; one row = 512 B = 32 float4

// ---------------------------------------------------------------------------
// Kernel 1: split gather. grid = NBATCH*SPLITS blocks, 256 threads.
// Block (b, s) sums leaf rows [s*63, s*63+lcnt) and idx1 rows [s*7, s*7+icnt)
// ws layout: ws[(b*4+s)*256 + 0..127]   = partial sum of leaf embeddings
//            ws[(b*4+s)*256 + 128..255] = partial sum of idx1 embeddings
// (raw sums; scaling to means happens in the finish kernel)
// ---------------------------------------------------------------------------
__global__ __launch_bounds__(256) void sage_gather(
    const float* __restrict__ emb,
    const int* __restrict__ idx1,
    const int* __restrict__ idx2,
    float* __restrict__ ws)
{
    const int blk  = blockIdx.x;
    const int b    = blk >> 2;
    const int s    = blk & 3;
    const int tid  = threadIdx.x;
    const int slot = tid >> 4;   // 0..15 : row slot
    const int cc   = tid & 15;   // 0..15 : 32-byte column chunk

    const int lstart = s * 63;
    const int lcnt   = (s == 3) ? (NLEAF - 3 * 63) : 63;  // 63,63,63,61
    const int istart = s * 7;
    const int icnt   = (s == 3) ? (N0 - 3 * 7) : 7;       // 7,7,7,4

    __shared__ int   sidx[80];        // [0..62] leaf slice, [64..70] idx1 slice
    __shared__ float red[16][128];    // cross-slot reduce buffer (8 KB)

    if (tid < lcnt)                   sidx[tid]      = idx2[b * NLEAF + lstart + tid];
    if (tid >= 64 && tid < 64 + icnt) sidx[tid]      = idx1[b * N0 + istart + (tid - 64)];
    __syncthreads();

    const char* embb = (const char*)emb;
    const uint32_t coff = (uint32_t)cc * 32u;

    float acc[8];
#pragma unroll
    for (int j = 0; j < 8; ++j) acc[j] = 0.f;

    // ---- leaf rows: k = slot + 16*i. i=0..2 always valid (slot+32 <= 47 < 61),
    //      i=3 predicated. Full unroll -> all loads issued up front (deep MLP).
#pragma unroll
    for (int i = 0; i < 3; ++i) {
        int id = sidx[slot + 16 * i];
        const float4* p = (const float4*)(embb + (uint32_t)id * 512u + coff);
        float4 v0 = p[0];
        float4 v1 = p[1];
        acc[0] += v0.x; acc[1] += v0.y; acc[2] += v0.z; acc[3] += v0.w;
        acc[4] += v1.x; acc[5] += v1.y; acc[6] += v1.z; acc[7] += v1.w;
    }
    if (slot + 48 < lcnt) {
        int id = sidx[slot + 48];
        const float4* p = (const float4*)(embb + (uint32_t)id * 512u + coff);
        float4 v0 = p[0];
        float4 v1 = p[1];
        acc[0] += v0.x; acc[1] += v0.y; acc[2] += v0.z; acc[3] += v0.w;
        acc[4] += v1.x; acc[5] += v1.y; acc[6] += v1.z; acc[7] += v1.w;
    }
#pragma unroll
    for (int j = 0; j < 8; ++j) red[slot][cc * 8 + j] = acc[j];
    __syncthreads();
    if (tid < 128) {
        float t = 0.f;
#pragma unroll
        for (int g = 0; g < 16; ++g) t += red[g][tid];
        ws[(size_t)blk * 256 + tid] = t;          // leaf partial sum
    }
    __syncthreads();

    // ---- idx1 rows: slot k = slot (only slots 0..icnt-1 active) --------------
#pragma unroll
    for (int j = 0; j < 8; ++j) acc[j] = 0.f;
    if (slot < icnt) {
        int id = sidx[64 + slot];
        const float4* p = (const float4*)(embb + (uint32_t)id * 512u + coff);
        float4 v0 = p[0];
        float4 v1 = p[1];
        acc[0] += v0.x; acc[1] += v0.y; acc[2] += v0.z; acc[3] += v0.w;
        acc[4] += v1.x; acc[5] += v1.y; acc[6] += v1.z; acc[7] += v1.w;
    }
#pragma unroll
    for (int j = 0; j < 8; ++j) red[slot][cc * 8 + j] = acc[j];
    __syncthreads();
    if (tid < 128) {
        float t = 0.f;
#pragma unroll
        for (int g = 0; g < 16; ++g) t += red[g][tid];
        ws[(size_t)blk * 256 + 128 + tid] = t;    // idx1 partial sum
    }
}

// ---------------------------------------------------------------------------
// Kernel 2: finish. grid = NBATCH blocks, 256 threads.
// Combines the 4 partials, gathers the root row, runs both GEMVs + sigmoid.
// ---------------------------------------------------------------------------
__global__ __launch_bounds__(256) void sage_finish(
    const float* __restrict__ emb,
    const float* __restrict__ W0,
    const float* __restrict__ b0,
    const float* __restrict__ W1,
    const int* __restrict__ roots,
    const float* __restrict__ ws,
    float* __restrict__ out)
{
    const int b   = blockIdx.x;
    const int tid = threadIdx.x;

    __shared__ float hr[128];        // root embedding
    __shared__ float m1[128];        // mean over idx1 rows
    __shared__ float m2[128];        // mean over idx2 rows
    __shared__ float tv[128];        // mean0 = concat(m1,m2) @ W1
    __shared__ float red2[2][128];

    // root row prefetch (issued first; consumed only in phase 2b)
    const int root = roots[b];
    if (tid < 32) {
        float4 v = ((const float4*)((const char*)emb + (uint32_t)root * 512u))[tid];
        ((float4*)hr)[tid] = v;
    }

    // combine partials: lower 128 = leaf sums -> m2, upper 128 = idx1 sums -> m1
    {
        float p = 0.f;
#pragma unroll
        for (int s = 0; s < SPLITS; ++s) p += ws[(size_t)b * 1024 + s * 256 + tid];
        if (tid < 128) m2[tid] = p * (1.0f / NLEAF);
        else           m1[tid - 128] = p * (1.0f / N0);
    }
    __syncthreads();

    const int c = tid & 127;
    const int h = tid >> 7;

    // ---- phase 2a: tv = concat(m1, m2) @ W1  (256 -> 128), split-K ---------
    {
        const float* xh = h ? m2 : m1;
        const float* w = W1 + (size_t)(h * 128) * 128 + c;
        float q = 0.f;
#pragma unroll 8
        for (int k = 0; k < 128; ++k) {
            q += xh[k] * w[(size_t)k * 128];
        }
        red2[h][c] = q;
    }
    __syncthreads();
    if (tid < 128) tv[tid] = red2[0][tid] + red2[1][tid];
    __syncthreads();

    // ---- phase 2b: z = concat(hr, tv) @ W0 + b0; sigmoid -------------------
    {
        const float* yh = h ? tv : hr;
        const float* w = W0 + (size_t)(h * 128) * 128 + c;
        float q = 0.f;
#pragma unroll 8
        for (int k = 0; k < 128; ++k) {
            q += yh[k] * w[(size_t)k * 128];
        }
        red2[h][c] = q;
    }
    __syncthreads();
    if (tid < 128) {
        float z = red2[0][tid] + red2[1][tid] + b0[tid];
        float sg = 1.0f / (1.0f + __expf(-z));
        out[(size_t)b * 128 + tid] = sg;
    }
}

extern "C" void kernel_launch(void* const* d_in, const int* in_sizes, int n_in,
                              void* d_out, int out_size, void* d_ws, size_t ws_size,
                              hipStream_t stream) {
    const float* emb   = (const float*)d_in[0];
    const float* W0    = (const float*)d_in[1];
    const float* b0    = (const float*)d_in[2];
    const float* W1    = (const float*)d_in[3];
    const int*   roots = (const int*)d_in[4];
    const int*   idx1  = (const int*)d_in[5];
    const int*   idx2  = (const int*)d_in[6];
    float* out = (float*)d_out;
    float* ws  = (float*)d_ws;   // needs 1024*4*256*4 = 4 MiB

    sage_gather<<<NBATCH * SPLITS, 256, 0, stream>>>(emb, idx1, idx2, ws);
    sage_finish<<<NBATCH, 256, 0, stream>>>(emb, W0, b0, W1, roots, ws, out);
}

// Round 2
// 590.893 us; speedup vs baseline: 1.0134x; 1.0134x over previous
//
#include <hip/hip_runtime.h>

#define NBATCH 1024
#define N0     25
#define N1     10
#define NLEAF  (N0 * N1)        // 250
#define NROWS  (NLEAF + N0 + 1) // 276 rows gathered per batch: leaves, idx1, root
// embedding dim = 128 f32; one row = 512 B = 32 float4

// One block per batch row. 256 threads = 8 row-slots x 32 column-chunks.
// Lane (slot, c4) reads float4 at byte c4*16 of row k = slot + 8*i:
// each wave VMEM instruction covers exactly 2 contiguous 512B rows
// (full 64B-sector utilization), vs the old stride-32 half-sector pattern.
__global__ __launch_bounds__(256) void sage_fused(
    const float* __restrict__ emb,    // [NODE_CNT+1][128] f32
    const float* __restrict__ W0,     // [256][128] f32
    const float* __restrict__ b0,     // [128] f32
    const float* __restrict__ W1,     // [256][128] f32
    const int* __restrict__ roots,    // [B]
    const int* __restrict__ idx1,     // [B][25]
    const int* __restrict__ idx2,     // [B][25][10]
    float* __restrict__ out)          // [B][128] f32
{
    const int b    = blockIdx.x;
    const int tid  = threadIdx.x;
    const int slot = tid >> 5;   // 0..7  : row slot
    const int c4   = tid & 31;   // 0..31 : 16-byte chunk (cols 4*c4..4*c4+3)

    __shared__ int   sidx[NROWS];    // [0..249] leaves, [250..274] idx1, [275] root
    __shared__ float red[8][256];    // cross-slot reduce: [.][0..127]=leaf, [.][128..255]=idx1
    __shared__ float hr[128];        // root embedding
    __shared__ float m1[128];        // mean over idx1 rows
    __shared__ float m2[128];        // mean over leaf rows
    __shared__ float tv[128];        // mean0 = concat(m1,m2) @ W1
    __shared__ float red2[2][128];

    // ---- stage all 276 indices (single barrier) ----------------------------
    if (tid < NLEAF) sidx[tid]         = idx2[b * NLEAF + tid];
    if (tid < N0)    sidx[NLEAF + tid] = idx1[b * N0 + tid];
    if (tid == 255)  sidx[NROWS - 1]   = roots[b];
    __syncthreads();

    const char* embb = (const char*)emb;
    const uint32_t coff = (uint32_t)c4 * 16u;

    float accL0 = 0.f, accL1 = 0.f, accL2 = 0.f, accL3 = 0.f;
    float accI0 = 0.f, accI1 = 0.f, accI2 = 0.f, accI3 = 0.f;

    // ---- merged gather: rows k = slot + 8*i --------------------------------
    // i = 0..30: k <= 247 < 250, always a leaf row (no branch)
#pragma unroll 8
    for (int i = 0; i < 31; ++i) {
        int id = sidx[slot + 8 * i];
        float4 v = *(const float4*)(embb + ((uint32_t)id * 512u + coff));
        accL0 += v.x; accL1 += v.y; accL2 += v.z; accL3 += v.w;
    }
    // i = 31..34: mixed leaf / idx1 / root / out-of-range tail
#pragma unroll
    for (int i = 31; i < 35; ++i) {
        int k = slot + 8 * i;
        if (k < NROWS) {
            int id = sidx[k];
            float4 v = *(const float4*)(embb + ((uint32_t)id * 512u + coff));
            if (k < NLEAF) {
                accL0 += v.x; accL1 += v.y; accL2 += v.z; accL3 += v.w;
            } else if (k < NROWS - 1) {
                accI0 += v.x; accI1 += v.y; accI2 += v.z; accI3 += v.w;
            } else {  // k == 275: root row (slot 3, i == 34)
                hr[c4 * 4 + 0] = v.x; hr[c4 * 4 + 1] = v.y;
                hr[c4 * 4 + 2] = v.z; hr[c4 * 4 + 3] = v.w;
            }
        }
    }
    red[slot][c4 * 4 + 0] = accL0;
    red[slot][c4 * 4 + 1] = accL1;
    red[slot][c4 * 4 + 2] = accL2;
    red[slot][c4 * 4 + 3] = accL3;
    red[slot][128 + c4 * 4 + 0] = accI0;
    red[slot][128 + c4 * 4 + 1] = accI1;
    red[slot][128 + c4 * 4 + 2] = accI2;
    red[slot][128 + c4 * 4 + 3] = accI3;
    __syncthreads();

    // ---- cross-slot reduce -> m2 (leaf mean), m1 (idx1 mean) ---------------
    {
        float s = 0.f;
#pragma unroll
        for (int g = 0; g < 8; ++g) s += red[g][tid];
        if (tid < 128) m2[tid] = s * (1.0f / NLEAF);
        else           m1[tid - 128] = s * (1.0f / N0);
    }
    __syncthreads();

    const int c = tid & 127;
    const int h = tid >> 7;

    // ---- phase 2a: tv = concat(m1, m2) @ W1  (256 -> 128), split-K ---------
    {
        const float* xh = h ? m2 : m1;
        const float* w = W1 + (size_t)(h * 128) * 128 + c;
        float q = 0.f;
#pragma unroll 8
        for (int k = 0; k < 128; ++k) {
            q += xh[k] * w[(size_t)k * 128];
        }
        red2[h][c] = q;
    }
    __syncthreads();
    if (tid < 128) tv[tid] = red2[0][tid] + red2[1][tid];
    __syncthreads();

    // ---- phase 2b: z = concat(hr, tv) @ W0 + b0; sigmoid -------------------
    {
        const float* yh = h ? tv : hr;
        const float* w = W0 + (size_t)(h * 128) * 128 + c;
        float q = 0.f;
#pragma unroll 8
        for (int k = 0; k < 128; ++k) {
            q += yh[k] * w[(size_t)k * 128];
        }
        red2[h][c] = q;
    }
    __syncthreads();
    if (tid < 128) {
        float z = red2[0][tid] + red2[1][tid] + b0[tid];
        float sg = 1.0f / (1.0f + __expf(-z));
        out[(size_t)b * 128 + tid] = sg;
    }
}

extern "C" void kernel_launch(void* const* d_in, const int* in_sizes, int n_in,
                              void* d_out, int out_size, void* d_ws, size_t ws_size,
                              hipStream_t stream) {
    const float* emb   = (const float*)d_in[0];
    const float* W0    = (const float*)d_in[1];
    const float* b0    = (const float*)d_in[2];
    const float* W1    = (const float*)d_in[3];
    const int*   roots = (const int*)d_in[4];
    const int*   idx1  = (const int*)d_in[5];
    const int*   idx2  = (const int*)d_in[6];
    float* out = (float*)d_out;

    sage_fused<<<NBATCH, 256, 0, stream>>>(emb, W0, b0, W1, roots, idx1, idx2, out);
}